// Round 20
// baseline (441.982 us; speedup 1.0000x reference)
//
#include <hip/hip_runtime.h>
#include <math.h>

#define LN_EPS 1e-5f
#define BN_EPS 1e-5f
#define QK_SCALE 0.1767766953f

typedef __attribute__((ext_vector_type(8))) short bf16x8;
typedef __attribute__((ext_vector_type(4))) float f32x4;

__device__ __forceinline__ unsigned short f2bf(float x) {
    union { float f; unsigned u; } v; v.f = x;
    unsigned r = v.u + 0x7FFFu + ((v.u >> 16) & 1u);
    return (unsigned short)(r >> 16);
}
__device__ __forceinline__ float bf2f(unsigned short h) {
    union { unsigned u; float f; } v; v.u = ((unsigned)h) << 16;
    return v.f;
}
__device__ __forceinline__ unsigned packbf(float a, float b) {
    return (unsigned)f2bf(a) | ((unsigned)f2bf(b) << 16);
}
#define FENCE() asm volatile("" ::: "memory")

// ============================================================================
// B=1, N=4, DIM=FDIM=128, H=W=256, FH=FW=32, QW 16x16, FW 2x2, HEADS=4, DH=32
// token-major activations: [(n*1024+p)*128 + c]
// Base = round-19 passing kernel (392us, absmax 0.03125). ONE change: k_mlp
// restructured to 128 tokens/block (grid 512), 2 token-tiles per wave — every
// weight-fragment load feeds 2 MFMAs (halves the per-token weight-load chain,
// k_mlp was 2x126us = 65% of runtime at MfmaUtil 2.6%). Hidden processed in
// four 64-wide quarters; K-chunk order 0..255 preserved => bit-exact.
// LDS = 53,248B (aT[128][136] + hT[128][72], both 16B-row-aligned).
// ============================================================================

// ---------------- kernel 0: pack weights to bf16 (+transposed wq) + cb ------
__global__ void k_pack(unsigned short* __restrict__ dst, float* __restrict__ cb,
    const float* wq1, const float* wp1, const float* wq2, const float* wp2,
    const float* m1w1, const float* m1w2, const float* m2w1, const float* m2w2,
    const float* fpw, const float* flw,
    const float* wk1, const float* wv1, const float* wk2, const float* wv2,
    const float* bev_b, const float* cam_w, const float* E_inv)
{
    int gid = blockIdx.x * 256 + threadIdx.x;
    if (gid < 294912) {
        const float* src; int off = gid;
        if      (off < 16384)  { src = wq1; }
        else if (off < 32768)  { src = wp1;  off -= 16384; }
        else if (off < 49152)  { src = wq2;  off -= 32768; }
        else if (off < 65536)  { src = wp2;  off -= 49152; }
        else if (off < 98304)  { src = m1w1; off -= 65536; }
        else if (off < 131072) { src = m1w2; off -= 98304; }
        else if (off < 163840) { src = m2w1; off -= 131072; }
        else if (off < 196608) { src = m2w2; off -= 163840; }
        else if (off < 212992) { src = fpw;  off -= 196608; }
        else if (off < 229376) { src = flw;  off -= 212992; }
        else if (off < 245760) { src = wk1;  off -= 229376; }
        else if (off < 262144) { src = wv1;  off -= 245760; }
        else if (off < 278528) { src = wk2;  off -= 262144; }
        else                   { src = wv2;  off -= 278528; }
        dst[gid] = f2bf(src[off]);
    } else if (gid < 311296) {
        int off = gid - 294912;                    // wq1^T: [in][out]
        dst[gid] = f2bf(wq1[(off & 127)*128 + (off >> 7)]);
    } else if (gid < 327680) {
        int off = gid - 311296;                    // wq2^T
        dst[gid] = f2bf(wq2[(off & 127)*128 + (off >> 7)]);
    } else if (gid < 328192) {
        int i = gid - 327680;
        int n = i >> 7, c = i & 127;
        const float* Ev = E_inv + n * 16;
        cb[i] = bev_b[c] - (cam_w[c*4+0]*Ev[3] + cam_w[c*4+1]*Ev[7]
                          + cam_w[c*4+2]*Ev[11] + cam_w[c*4+3]*Ev[15]);
    }
}

// ---------------- kernel 1: img_embed, token-major --------------------------
__global__ void k_img_embed(const float* __restrict__ I_inv,
                            const float* __restrict__ E_inv,
                            const float* __restrict__ img_w,
                            const float* __restrict__ cam_w,
                            float* __restrict__ img_embed)
{
    const int blk = blockIdx.x;          // n*1024 + p, p = fy*32+fx
    const int n = blk >> 10, p = blk & 1023;
    const int fy = p >> 5, fx = p & 31;
    const float px = fx * (256.0f / 31.0f);
    const float py = fy * (256.0f / 31.0f);
    const float* Iv = I_inv + n * 9;
    const float* Ev = E_inv + n * 16;
    const float c0 = Iv[0]*px + Iv[1]*py + Iv[2];
    const float c1 = Iv[3]*px + Iv[4]*py + Iv[5];
    const float c2 = Iv[6]*px + Iv[7]*py + Iv[8];
    const float d0 = Ev[0]*c0 + Ev[1]*c1 + Ev[2]*c2 + Ev[3];
    const float d1 = Ev[4]*c0 + Ev[5]*c1 + Ev[6]*c2 + Ev[7];
    const float d2 = Ev[8]*c0 + Ev[9]*c1 + Ev[10]*c2 + Ev[11];
    const float d3 = Ev[12]*c0 + Ev[13]*c1 + Ev[14]*c2 + Ev[15];
    const int c = threadIdx.x;
    const float ce = cam_w[c*4+0]*Ev[3] + cam_w[c*4+1]*Ev[7]
                   + cam_w[c*4+2]*Ev[11] + cam_w[c*4+3]*Ev[15];
    float v = img_w[c*4+0]*d0 + img_w[c*4+1]*d1
            + img_w[c*4+2]*d2 + img_w[c*4+3]*d3 - ce;
    __shared__ float red[128];
    red[c] = v * v;
    __syncthreads();
    for (int s = 64; s > 0; s >>= 1) {
        if (c < s) red[c] += red[c + s];
        __syncthreads();
    }
    img_embed[(n*1024 + p)*128 + c] = v / (sqrtf(red[0]) + 1e-7f);
}

// ---------------- kernel 2: key/val = BN+ReLU + MFMA 1x1 conv ---------------
__global__ __launch_bounds__(256) void k_keyval(
    const float* __restrict__ feature,
    const float* __restrict__ img_embed,
    const float* __restrict__ fp_g, const float* __restrict__ fp_b,
    const float* __restrict__ fp_m, const float* __restrict__ fp_v,
    const unsigned short* __restrict__ fpw,
    const float* __restrict__ fl_g, const float* __restrict__ fl_b,
    const float* __restrict__ fl_m, const float* __restrict__ fl_v,
    const unsigned short* __restrict__ flw,
    float* __restrict__ key, float* __restrict__ val)
{
    __shared__ __align__(16) unsigned short aP[64*136];
    __shared__ __align__(16) unsigned short aL[64*136];
    const int n = blockIdx.x >> 4, p0 = (blockIdx.x & 15) * 64;
    const int tid = threadIdx.x;

    for (int idx = tid; idx < 8192; idx += 256) {
        int c = idx >> 6, dt = idx & 63;
        float f = feature[(n*128 + c)*1024 + p0 + dt];
        float xp = (f - fp_m[c]) * rsqrtf(fp_v[c] + BN_EPS) * fp_g[c] + fp_b[c];
        float xl = (f - fl_m[c]) * rsqrtf(fl_v[c] + BN_EPS) * fl_g[c] + fl_b[c];
        aP[dt*136 + c] = f2bf(fmaxf(xp, 0.f));
        aL[dt*136 + c] = f2bf(fmaxf(xl, 0.f));
    }
    __syncthreads();

    const int lane = tid & 63, wid = tid >> 6;
    const int lr = lane & 15, lg = lane >> 4;
    const int wtb = wid * 16;
    f32x4 ak[8], av[8];
    const f32x4 z4 = {0.f, 0.f, 0.f, 0.f};
#pragma unroll
    for (int nf = 0; nf < 8; nf++) { ak[nf] = z4; av[nf] = z4; }
#pragma unroll
    for (int kst = 0; kst < 4; kst++) {
        bf16x8 a1 = *(const bf16x8*)&aP[(wtb+lr)*136 + kst*32 + lg*8];
        bf16x8 a2 = *(const bf16x8*)&aL[(wtb+lr)*136 + kst*32 + lg*8];
#pragma unroll
        for (int nf = 0; nf < 8; nf++) {
            bf16x8 bK = *(const bf16x8*)&fpw[(nf*16+lr)*128 + kst*32 + lg*8];
            bf16x8 bV = *(const bf16x8*)&flw[(nf*16+lr)*128 + kst*32 + lg*8];
            ak[nf] = __builtin_amdgcn_mfma_f32_16x16x32_bf16(a1, bK, ak[nf], 0, 0, 0);
            av[nf] = __builtin_amdgcn_mfma_f32_16x16x32_bf16(a2, bV, av[nf], 0, 0, 0);
        }
    }
#pragma unroll
    for (int nf = 0; nf < 8; nf++) {
#pragma unroll
        for (int rr = 0; rr < 4; rr++) {
            int g = (n*1024 + p0 + wtb + lg*4 + rr)*128 + nf*16 + lr;
            key[g] = ak[nf][rr] + img_embed[g];
            val[g] = av[nf][rr];
        }
    }
}

// ---------------- kernel 3: k/v LN + MFMA projection (grid 256, 1 proj/blk) -
__global__ __launch_bounds__(256) void k_kvproj(
    const float* __restrict__ key, const float* __restrict__ val,
    const float* __restrict__ k1g, const float* __restrict__ k1b,
    const unsigned short* __restrict__ wk1, const float* __restrict__ bk1,
    const float* __restrict__ v1g, const float* __restrict__ v1b,
    const unsigned short* __restrict__ wv1, const float* __restrict__ bv1,
    const float* __restrict__ k2g, const float* __restrict__ k2b,
    const unsigned short* __restrict__ wk2, const float* __restrict__ bk2,
    const float* __restrict__ v2g, const float* __restrict__ v2b,
    const unsigned short* __restrict__ wv2, const float* __restrict__ bv2,
    float* __restrict__ kp1, float* __restrict__ vp1,
    float* __restrict__ kp2, float* __restrict__ vp2)
{
    __shared__ __align__(16) unsigned short tile[64*136];
    const int pj = blockIdx.x >> 6;            // 0:k1 1:v1 2:k2 3:v2
    const int tok0 = (blockIdx.x & 63) * 64;
    const int tid = threadIdx.x;
    const int t = tid >> 2, part = tid & 3;

    const float* gsel[4] = {k1g, v1g, k2g, v2g};
    const float* asel[4] = {k1b, v1b, k2b, v2b};
    const unsigned short* wsel[4] = {wk1, wv1, wk2, wv2};
    const float* bsel[4] = {bk1, bv1, bk2, bv2};
    float* osel[4] = {kp1, vp1, kp2, vp2};
    const float* src = (pj & 1) ? val : key;
    const float* g  = gsel[pj];
    const float* ba = asel[pj];

    float rr_[32];
    float s1 = 0.f, s2 = 0.f;
#pragma unroll
    for (int k4 = 0; k4 < 8; k4++) {
        float4 a = *(const float4*)&src[(tok0+t)*128 + part*32 + k4*4];
        rr_[k4*4+0]=a.x; rr_[k4*4+1]=a.y; rr_[k4*4+2]=a.z; rr_[k4*4+3]=a.w;
        s1 += a.x+a.y+a.z+a.w; s2 += a.x*a.x+a.y*a.y+a.z*a.z+a.w*a.w;
    }
    s1 += __shfl_xor(s1, 1); s1 += __shfl_xor(s1, 2);
    s2 += __shfl_xor(s2, 1); s2 += __shfl_xor(s2, 2);
    const float mean = s1*(1.f/128.f);
    const float var  = s2*(1.f/128.f) - mean*mean;
    const float rstd = rsqrtf(var + LN_EPS);
#pragma unroll
    for (int k = 0; k < 32; k++) {
        int c = part*32 + k;
        float hat = (rr_[k]-mean)*rstd;
        tile[t*136 + c] = f2bf(hat*g[c] + ba[c]);
    }
    FENCE();   // wave-private rows

    const int lane = tid & 63, wid = tid >> 6;
    const int lr = lane & 15, lg = lane >> 4;
    const int wtb = wid * 16;
    const unsigned short* wp_ = wsel[pj];
    const f32x4 z4 = {0.f, 0.f, 0.f, 0.f};
    f32x4 acc[8];
#pragma unroll
    for (int nf = 0; nf < 8; nf++) acc[nf] = z4;
#pragma unroll
    for (int kst = 0; kst < 4; kst++) {
        bf16x8 a = *(const bf16x8*)&tile[(wtb+lr)*136 + kst*32 + lg*8];
#pragma unroll
        for (int nf = 0; nf < 8; nf++) {
            bf16x8 b = *(const bf16x8*)&wp_[(nf*16+lr)*128 + kst*32 + lg*8];
            acc[nf] = __builtin_amdgcn_mfma_f32_16x16x32_bf16(a, b, acc[nf], 0, 0, 0);
        }
    }
    float* outp = osel[pj];
#pragma unroll
    for (int nf = 0; nf < 8; nf++) {
        float bb = bsel[pj][nf*16 + lr];
#pragma unroll
        for (int rr2 = 0; rr2 < 4; rr2++)
            outp[(tok0 + wtb + lg*4 + rr2)*128 + nf*16 + lr] = acc[nf][rr2] + bb;
    }
}

// ---------------- kernel 3.5: per-window M = scale*(K @ Wq_hd), Mb ----------
__global__ __launch_bounds__(256) void k_mwin(
    const float* __restrict__ kp1, const float* __restrict__ kp2,
    const unsigned short* __restrict__ wq1T, const unsigned short* __restrict__ wq2T,
    const float* __restrict__ bq1, const float* __restrict__ bq2,
    unsigned short* __restrict__ Mw1, unsigned short* __restrict__ Mw2,
    float* __restrict__ Mb1, float* __restrict__ Mb2)
{
    __shared__ __align__(16) unsigned short kt[16*136];
    const int blk = blockIdx.x;
    const int stage = blk >> 8, win = blk & 255;
    const int wx = win >> 4, wy = win & 15;
    const int tid = threadIdx.x;

    const float* kp = stage ? kp2 : kp1;
    const unsigned short* wqT = stage ? wq2T : wq1T;
    const float* bq = stage ? bq2 : bq1;
    unsigned short* Mw = stage ? Mw2 : Mw1;
    float* Mb = stage ? Mb2 : Mb1;

    for (int idx = tid; idx < 2048; idx += 256) {
        int c = idx & 127, j = idx >> 7;
        int nk = j >> 2, f1 = (j >> 1) & 1, f2 = j & 1;
        int tok = stage ? (nk*1024 + (f1*16+wx)*32 + (f2*16+wy))
                        : (nk*1024 + (wx*2+f1)*32 + (wy*2+f2));
        kt[j*136 + c] = f2bf(kp[tok*128 + c]);
    }
    __syncthreads();

    const int lane = tid & 63, wid = tid >> 6;
    const int lr = lane & 15, lg = lane >> 4;
    const f32x4 z4 = {0.f, 0.f, 0.f, 0.f};
#pragma unroll
    for (int cc = 0; cc < 2; cc++) {
        int ct = wid*2 + cc;
#pragma unroll
        for (int hd = 0; hd < 4; hd++) {
            bf16x8 a = *(const bf16x8*)&kt[lr*136 + hd*32 + lg*8];
            bf16x8 b = *(const bf16x8*)&wqT[(ct*16+lr)*128 + hd*32 + lg*8];
            f32x4 acc = __builtin_amdgcn_mfma_f32_16x16x32_bf16(a, b, z4, 0, 0, 0);
#pragma unroll
            for (int rr = 0; rr < 4; rr++)
                Mw[((win*4 + hd)*16 + lg*4 + rr)*128 + ct*16 + lr]
                    = f2bf(acc[rr] * QK_SCALE);
        }
    }
    if (tid < 64) {
        int hd = tid >> 4, ky = tid & 15;
        float s = 0.f;
        for (int d = 0; d < 32; d++)
            s += bq[hd*32 + d] * bf2f(kt[ky*136 + hd*32 + d]);
        Mb[win*64 + tid] = s * QK_SCALE;
    }
}

// ---------------- kernel 4: stage-1 attention, hoisted/LDS-staged qgen ------
__global__ __launch_bounds__(256) void k_attn1(
    const float* __restrict__ x,
    const float* __restrict__ vp,
    const unsigned short* __restrict__ mw, const float* __restrict__ mb,
    const float* __restrict__ bev_w, const float* __restrict__ cb,
    const float* __restrict__ nqg, const float* __restrict__ nqb,
    const unsigned short* __restrict__ wpp, const float* __restrict__ bp,
    float* __restrict__ z1)
{
    __shared__ __align__(16) unsigned short aT[64*136];
    __shared__ __align__(16) unsigned short mws[64*136];    // staged Mw window
    __shared__ __align__(16) unsigned short vbT[128*24];
    __shared__ __align__(16) unsigned short xbuf[64*132];   // bf16 residual
    __shared__ float mbs[64];
    __shared__ float cbs[512];                              // [4][128] cb
    __shared__ float nqgs[128];
    __shared__ float nqbs[128];

    const int blk = blockIdx.x;
    const int win = blk >> 2, rg = blk & 3;
    const int wx = win >> 4, wy = win & 15;
    const int tid = threadIdx.x;
    const int lane = tid & 63, wid = tid >> 6;
    const int lr = lane & 15, lg = lane >> 4;
    const int wtb = wid * 16;

    // V^T tile (bf16) for PV B-frags
    for (int idx = tid; idx < 2048; idx += 256) {
        int c = idx & 127, j = idx >> 7;
        int nk = j >> 2, f1 = (j >> 1) & 1, f2 = j & 1;
        int src = (nk*1024 + (wx*2+f1)*32 + (wy*2+f2))*128 + c;
        vbT[c*24 + j] = f2bf(vp[src]);
    }
    // stage the window's Mw tile (4 heads x 16 keys x 128) coalesced, bit-exact
    {
        const unsigned short* mwsrc = mw + win*8192;
        for (int idx = tid; idx < 2048; idx += 256) {
            int row = idx >> 5, c4 = (idx & 31)*4;
            *(ushort4*)&mws[row*136 + c4] = *(const ushort4*)&mwsrc[row*128 + c4];
        }
    }
    // coalesced bf16 x staging (residual only; r10-proven)
    for (int idx = tid; idx < 8192; idx += 256) {
        int tt = idx & 63, c = idx >> 6;
        int hh = wx*16 + rg*4 + (tt >> 4), ww = wy*16 + (tt & 15);
        xbuf[tt*132 + c] = f2bf(x[c*65536 + hh*256 + ww]);
    }
    if (tid < 64) mbs[tid] = mb[win*64 + tid];
    // stage small per-view tables (bit-exact values)
    for (int idx = tid; idx < 512; idx += 256) cbs[idx] = cb[idx];
    if (tid < 128) { nqgs[tid] = nqg[tid]; nqbs[tid] = nqb[tid]; }

    const int t = tid >> 2, part = tid & 3;
    const int w1 = rg*4 + (t >> 4), w2 = t & 15;
    const int h = wx*16 + w1, w = wy*16 + w2;
    const float world0 = 50.f - (float)h * (100.f/255.f);
    const float world1 = 50.f - (float)w * (100.f/255.f);

    // qgen xv: direct global f32 read, (t,part) mapping (4 full lines/instr)
    float xv[32];
#pragma unroll
    for (int k = 0; k < 32; k++) xv[k] = x[(part*32+k)*65536 + h*256 + w];
    // hoisted view-invariant bev_w dot (read once, not 4x)
    float base_[32];
#pragma unroll
    for (int k = 0; k < 32; k++) {
        int c = part*32 + k;
        base_[k] = bev_w[c*2+0]*world0 + bev_w[c*2+1]*world1;
    }
    __syncthreads();    // the ONLY barrier (vbT/mws/xbuf/mbs/cbs/nqgs/nqbs)

    f32x4 aacc[4][2];
    const f32x4 z4 = {0.f, 0.f, 0.f, 0.f};
#pragma unroll
    for (int hd = 0; hd < 4; hd++) { aacc[hd][0] = z4; aacc[hd][1] = z4; }

    uint2 pa[4], pb[4];

    // per-view: qgen -> aT (wave-private rows), scores via LDS mws, softmax
    auto do_view = [&](int n, uint2* pp) {
        float r[32]; float ss = 0.f;
#pragma unroll
        for (int k = 0; k < 32; k++) {
            int c = part*32 + k;
            float e = base_[k] + cbs[n*128 + c];
            r[k] = e; ss += e*e;
        }
        ss += __shfl_xor(ss, 1); ss += __shfl_xor(ss, 2);
        const float invn = 1.f / (sqrtf(ss) + 1e-7f);
        float s1 = 0.f, s2 = 0.f;
#pragma unroll
        for (int k = 0; k < 32; k++) {
            float qv = r[k]*invn + xv[k];
            r[k] = qv; s1 += qv; s2 += qv*qv;
        }
        s1 += __shfl_xor(s1, 1); s1 += __shfl_xor(s1, 2);
        s2 += __shfl_xor(s2, 1); s2 += __shfl_xor(s2, 2);
        const float mean = s1*(1.f/128.f);
        const float var  = s2*(1.f/128.f) - mean*mean;
        const float rstd = rsqrtf(var + LN_EPS);
#pragma unroll
        for (int k4 = 0; k4 < 8; k4++) {
            int c = part*32 + k4*4;
            ushort4 u;
            u.x = f2bf((r[k4*4+0]-mean)*rstd*nqgs[c+0] + nqbs[c+0]);
            u.y = f2bf((r[k4*4+1]-mean)*rstd*nqgs[c+1] + nqbs[c+1]);
            u.z = f2bf((r[k4*4+2]-mean)*rstd*nqgs[c+2] + nqbs[c+2]);
            u.w = f2bf((r[k4*4+3]-mean)*rstd*nqgs[c+3] + nqbs[c+3]);
            *(ushort4*)&aT[t*136 + c] = u;
        }
        FENCE();

        f32x4 sacc[4];
#pragma unroll
        for (int hd = 0; hd < 4; hd++) sacc[hd] = z4;
#pragma unroll
        for (int kst = 0; kst < 4; kst++) {
            bf16x8 bq_ = *(const bf16x8*)&aT[(wtb+lr)*136 + kst*32 + lg*8];
#pragma unroll
            for (int hd = 0; hd < 4; hd++) {
                bf16x8 am = *(const bf16x8*)&mws[(hd*16 + lr)*136 + kst*32 + lg*8];
                sacc[hd] = __builtin_amdgcn_mfma_f32_16x16x32_bf16(am, bq_, sacc[hd], 0, 0, 0);
            }
        }
#pragma unroll
        for (int hd = 0; hd < 4; hd++) {
            float e0 = sacc[hd][0] + mbs[hd*16 + lg*4 + 0];
            float e1 = sacc[hd][1] + mbs[hd*16 + lg*4 + 1];
            float e2 = sacc[hd][2] + mbs[hd*16 + lg*4 + 2];
            float e3 = sacc[hd][3] + mbs[hd*16 + lg*4 + 3];
            float mx = fmaxf(fmaxf(e0, e1), fmaxf(e2, e3));
            mx = fmaxf(mx, __shfl_xor(mx, 16));
            mx = fmaxf(mx, __shfl_xor(mx, 32));
            e0 = __expf(e0-mx); e1 = __expf(e1-mx);
            e2 = __expf(e2-mx); e3 = __expf(e3-mx);
            float sum = e0+e1+e2+e3;
            sum += __shfl_xor(sum, 16);
            sum += __shfl_xor(sum, 32);
            float is = 1.f/sum;
            pp[hd] = make_uint2(packbf(e0*is, e1*is), packbf(e2*is, e3*is));
        }
        FENCE();
    };

    // PV for a view pair: K=32 = [viewA 16 keys | viewB 16 keys], B=[V;V]
    auto pv_pair = [&]() {
        const int s0 = (lg & 1)*32 + lr;
        const int s1 = s0 + 16;
        const bool hi = (lg >> 1) != 0;
#pragma unroll
        for (int hd = 0; hd < 4; hd++) {
            unsigned a00 = __shfl(pa[hd].x, s0), a01 = __shfl(pa[hd].y, s0);
            unsigned a10 = __shfl(pa[hd].x, s1), a11 = __shfl(pa[hd].y, s1);
            unsigned b00 = __shfl(pb[hd].x, s0), b01 = __shfl(pb[hd].y, s0);
            unsigned b10 = __shfl(pb[hd].x, s1), b11 = __shfl(pb[hd].y, s1);
            union { unsigned u[4]; bf16x8 v; } af;
            af.u[0] = hi ? b00 : a00; af.u[1] = hi ? b01 : a01;
            af.u[2] = hi ? b10 : a10; af.u[3] = hi ? b11 : a11;
#pragma unroll
            for (int dt = 0; dt < 2; dt++) {
                bf16x8 bv = *(const bf16x8*)&vbT[(hd*32+dt*16+lr)*24 + (lg&1)*8];
                aacc[hd][dt] = __builtin_amdgcn_mfma_f32_16x16x32_bf16(af.v, bv, aacc[hd][dt], 0, 0, 0);
            }
        }
    };

    do_view(0, pa); do_view(1, pb); pv_pair();
    do_view(2, pa); do_view(3, pb); pv_pair();

    // view-mean att -> aT (wave-private rows)
#pragma unroll
    for (int hd = 0; hd < 4; hd++)
#pragma unroll
        for (int dt = 0; dt < 2; dt++)
#pragma unroll
            for (int rr = 0; rr < 4; rr++)
                aT[(wtb + lg*4 + rr)*136 + hd*32 + dt*16 + lr]
                    = f2bf(aacc[hd][dt][rr] * 0.25f);
    FENCE();

    // out-projection + residual (bf16 from xbuf, r10-proven)
    f32x4 acc[8];
#pragma unroll
    for (int nf = 0; nf < 8; nf++) acc[nf] = z4;
#pragma unroll
    for (int kst = 0; kst < 4; kst++) {
        bf16x8 a = *(const bf16x8*)&aT[(wtb+lr)*136 + kst*32 + lg*8];
#pragma unroll
        for (int nf = 0; nf < 8; nf++) {
            bf16x8 b = *(const bf16x8*)&wpp[(nf*16+lr)*128 + kst*32 + lg*8];
            acc[nf] = __builtin_amdgcn_mfma_f32_16x16x32_bf16(a, b, acc[nf], 0, 0, 0);
        }
    }
#pragma unroll
    for (int nf = 0; nf < 8; nf++) {
        float bpv = bp[nf*16 + lr];
#pragma unroll
        for (int rr = 0; rr < 4; rr++) {
            int tt = wtb + lg*4 + rr;
            int hh = wx*16 + rg*4 + (tt >> 4), ww = wy*16 + (tt & 15);
            float res = bf2f(xbuf[tt*132 + nf*16 + lr]);
            z1[(hh*256+ww)*128 + nf*16 + lr] = acc[nf][rr] + bpv + res;
        }
    }
}

// ---------------- kernel 6: stage-2 attention, 1 barrier --------------------
__global__ __launch_bounds__(256) void k_attn2(
    const float* __restrict__ z1,
    const float* __restrict__ vp,
    const unsigned short* __restrict__ mw, const float* __restrict__ mb,
    const float* __restrict__ nqg, const float* __restrict__ nqb,
    const unsigned short* __restrict__ wpp, const float* __restrict__ bp,
    float* __restrict__ z2)
{
    __shared__ __align__(16) unsigned short aT[64*136];
    __shared__ __align__(16) unsigned short vbT[128*24];
    __shared__ float mbs[64];

    const int blk = blockIdx.x;
    const int win = blk >> 2, rg = blk & 3;
    const int wx = win >> 4, wy = win & 15;
    const int tid = threadIdx.x;
    const int lane = tid & 63, wid = tid >> 6;
    const int lr = lane & 15, lg = lane >> 4;
    const int wtb = wid * 16;

    for (int idx = tid; idx < 2048; idx += 256) {
        int c = idx & 127, j = idx >> 7;
        int nk = j >> 2, f1 = (j >> 1) & 1, f2 = j & 1;
        int src = (nk*1024 + (f1*16+wx)*32 + (f2*16+wy))*128 + c;
        vbT[c*24 + j] = f2bf(vp[src]);
    }
    if (tid < 64) mbs[tid] = mb[win*64 + tid];

    const int t = tid >> 2, part = tid & 3;
    const int w1 = rg*4 + (t >> 4), w2 = t & 15;
    const int h = wx*16 + w1, w = wy*16 + w2;
    const float* zr = z1 + (h*256 + w)*128 + part*32;

    float r[32]; float s1 = 0.f, s2 = 0.f;
#pragma unroll
    for (int k4 = 0; k4 < 8; k4++) {
        float4 v = *(const float4*)&zr[k4*4];
        r[k4*4+0]=v.x; r[k4*4+1]=v.y; r[k4*4+2]=v.z; r[k4*4+3]=v.w;
        s1 += v.x+v.y+v.z+v.w;
        s2 += v.x*v.x+v.y*v.y+v.z*v.z+v.w*v.w;
    }
    s1 += __shfl_xor(s1, 1); s1 += __shfl_xor(s1, 2);
    s2 += __shfl_xor(s2, 1); s2 += __shfl_xor(s2, 2);
    const float mean = s1*(1.f/128.f);
    const float var  = s2*(1.f/128.f) - mean*mean;
    const float rstd = rsqrtf(var + LN_EPS);
#pragma unroll
    for (int k4 = 0; k4 < 8; k4++) {
        int c = part*32 + k4*4;
        ushort4 u;
        u.x = f2bf((r[k4*4+0]-mean)*rstd*nqg[c+0] + nqb[c+0]);
        u.y = f2bf((r[k4*4+1]-mean)*rstd*nqg[c+1] + nqb[c+1]);
        u.z = f2bf((r[k4*4+2]-mean)*rstd*nqg[c+2] + nqb[c+2]);
        u.w = f2bf((r[k4*4+3]-mean)*rstd*nqg[c+3] + nqb[c+3]);
        *(ushort4*)&aT[t*136 + c] = u;
    }
    __syncthreads();    // the ONLY barrier (vbT/mbs)

    const f32x4 z4 = {0.f, 0.f, 0.f, 0.f};
    f32x4 sacc[4];
#pragma unroll
    for (int hd = 0; hd < 4; hd++) sacc[hd] = z4;
#pragma unroll
    for (int kst = 0; kst < 4; kst++) {
        bf16x8 bq_ = *(const bf16x8*)&aT[(wtb+lr)*136 + kst*32 + lg*8];
#pragma unroll
        for (int hd = 0; hd < 4; hd++) {
            bf16x8 am = *(const bf16x8*)&mw[((win*4+hd)*16 + lr)*128 + kst*32 + lg*8];
            sacc[hd] = __builtin_amdgcn_mfma_f32_16x16x32_bf16(am, bq_, sacc[hd], 0, 0, 0);
        }
    }
    uint2 pa[4];
#pragma unroll
    for (int hd = 0; hd < 4; hd++) {
        float e0 = sacc[hd][0] + mbs[hd*16 + lg*4 + 0];
        float e1 = sacc[hd][1] + mbs[hd*16 + lg*4 + 1];
        float e2 = sacc[hd][2] + mbs[hd*16 + lg*4 + 2];
        float e3 = sacc[hd][3] + mbs[hd*16 + lg*4 + 3];
        float mx = fmaxf(fmaxf(e0, e1), fmaxf(e2, e3));
        mx = fmaxf(mx, __shfl_xor(mx, 16));
        mx = fmaxf(mx, __shfl_xor(mx, 32));
        e0 = __expf(e0-mx); e1 = __expf(e1-mx);
        e2 = __expf(e2-mx); e3 = __expf(e3-mx);
        float sum = e0+e1+e2+e3;
        sum += __shfl_xor(sum, 16);
        sum += __shfl_xor(sum, 32);
        float is = 1.f/sum;
        pa[hd] = make_uint2(packbf(e0*is, e1*is), packbf(e2*is, e3*is));
    }

    // PV: single view, upper 16 k-slots zero
    f32x4 aacc[4][2];
#pragma unroll
    for (int hd = 0; hd < 4; hd++) { aacc[hd][0] = z4; aacc[hd][1] = z4; }
    {
        const int s0 = (lg & 1)*32 + lr;
        const int s1_ = s0 + 16;
        const bool hi = (lg >> 1) != 0;
#pragma unroll
        for (int hd = 0; hd < 4; hd++) {
            unsigned a00 = __shfl(pa[hd].x, s0), a01 = __shfl(pa[hd].y, s0);
            unsigned a10 = __shfl(pa[hd].x, s1_), a11 = __shfl(pa[hd].y, s1_);
            union { unsigned u[4]; bf16x8 v; } af;
            af.u[0] = hi ? 0u : a00; af.u[1] = hi ? 0u : a01;
            af.u[2] = hi ? 0u : a10; af.u[3] = hi ? 0u : a11;
#pragma unroll
            for (int dt = 0; dt < 2; dt++) {
                bf16x8 bv = *(const bf16x8*)&vbT[(hd*32+dt*16+lr)*24 + (lg&1)*8];
                aacc[hd][dt] = __builtin_amdgcn_mfma_f32_16x16x32_bf16(af.v, bv, aacc[hd][dt], 0, 0, 0);
            }
        }
    }
    FENCE();
#pragma unroll
    for (int hd = 0; hd < 4; hd++)
#pragma unroll
        for (int dt = 0; dt < 2; dt++)
#pragma unroll
            for (int rr = 0; rr < 4; rr++)
                aT[(wtb + lg*4 + rr)*136 + hd*32 + dt*16 + lr]
                    = f2bf(aacc[hd][dt][rr]);
    FENCE();

    f32x4 acc[8];
#pragma unroll
    for (int nf = 0; nf < 8; nf++) acc[nf] = z4;
#pragma unroll
    for (int kst = 0; kst < 4; kst++) {
        bf16x8 a = *(const bf16x8*)&aT[(wtb+lr)*136 + kst*32 + lg*8];
#pragma unroll
        for (int nf = 0; nf < 8; nf++) {
            bf16x8 b = *(const bf16x8*)&wpp[(nf*16+lr)*128 + kst*32 + lg*8];
            acc[nf] = __builtin_amdgcn_mfma_f32_16x16x32_bf16(a, b, acc[nf], 0, 0, 0);
        }
    }
#pragma unroll
    for (int nf = 0; nf < 8; nf++) {
        float bpv = bp[nf*16 + lr];
#pragma unroll
        for (int rr = 0; rr < 4; rr++) {
            int tt = wtb + lg*4 + rr;
            int hh = wx*16 + rg*4 + (tt >> 4), ww = wy*16 + (tt & 15);
            int gi = (hh*256+ww)*128 + nf*16 + lr;
            z2[gi] = acc[nf][rr] + bpv + z1[gi];   // exact f32 residual
        }
    }
}

// ---------------- kernel 5/7: residual MLP, 128 tok/blk, 2 tiles/wave -------
__global__ __launch_bounds__(256) void k_mlp(
    float* __restrict__ z,
    const float* __restrict__ g, const float* __restrict__ bta,
    const unsigned short* __restrict__ w1p, const float* __restrict__ b1,
    const unsigned short* __restrict__ w2p, const float* __restrict__ b2)
{
    __shared__ __align__(16) unsigned short aT[128*136];  // 34,816 B
    __shared__ __align__(16) unsigned short hT[128*72];   // 18,432 B (quarter)
    const int base = blockIdx.x * 128;
    const int tid = threadIdx.x;
    const int t = tid >> 2, part = tid & 3;

    // LN for two 64-row tiles (identical per-row arithmetic to proven version)
#pragma unroll
    for (int rt = 0; rt < 2; rt++) {
        const float* zr = z + (base + rt*64 + t)*128 + part*32;
        float r[32]; float s1 = 0.f, s2 = 0.f;
#pragma unroll
        for (int k4 = 0; k4 < 8; k4++) {
            float4 v = *(const float4*)&zr[k4*4];
            r[k4*4+0]=v.x; r[k4*4+1]=v.y; r[k4*4+2]=v.z; r[k4*4+3]=v.w;
            s1 += v.x+v.y+v.z+v.w;
            s2 += v.x*v.x+v.y*v.y+v.z*v.z+v.w*v.w;
        }
        s1 += __shfl_xor(s1, 1); s1 += __shfl_xor(s1, 2);
        s2 += __shfl_xor(s2, 1); s2 += __shfl_xor(s2, 2);
        const float mean = s1*(1.f/128.f);
        const float var  = s2*(1.f/128.f) - mean*mean;
        const float rstd = rsqrtf(var + LN_EPS);
#pragma unroll
        for (int k4 = 0; k4 < 8; k4++) {
            int c = part*32 + k4*4;
            ushort4 u;
            u.x = f2bf((r[k4*4+0]-mean)*rstd*g[c+0] + bta[c+0]);
            u.y = f2bf((r[k4*4+1]-mean)*rstd*g[c+1] + bta[c+1]);
            u.z = f2bf((r[k4*4+2]-mean)*rstd*g[c+2] + bta[c+2]);
            u.w = f2bf((r[k4*4+3]-mean)*rstd*g[c+3] + bta[c+3]);
            *(ushort4*)&aT[(rt*64 + t)*136 + c] = u;
        }
    }
    __syncthreads();

    const int lane = tid & 63, wid = tid >> 6;
    const int lr = lane & 15, lg = lane >> 4;
    const int wtb = wid * 16;
    const f32x4 z4 = {0.f, 0.f, 0.f, 0.f};

    f32x4 oacc[2][8];
#pragma unroll
    for (int rt = 0; rt < 2; rt++)
#pragma unroll
        for (int nf = 0; nf < 8; nf++) oacc[rt][nf] = z4;

    // hidden in four 64-wide quarters; K-chunk order 0..255 preserved
#pragma unroll
    for (int q = 0; q < 4; q++) {
        // stage 1: hidden quarter = A @ W1[q]^T (each B-load feeds 2 tiles)
        f32x4 acc[2][4];
#pragma unroll
        for (int rt = 0; rt < 2; rt++)
#pragma unroll
            for (int nf = 0; nf < 4; nf++) acc[rt][nf] = z4;
#pragma unroll
        for (int kst = 0; kst < 4; kst++) {
            bf16x8 a0 = *(const bf16x8*)&aT[(wtb+lr)*136 + kst*32 + lg*8];
            bf16x8 a1 = *(const bf16x8*)&aT[(64+wtb+lr)*136 + kst*32 + lg*8];
#pragma unroll
            for (int nf = 0; nf < 4; nf++) {
                bf16x8 b = *(const bf16x8*)&w1p[((q*4+nf)*16+lr)*128 + kst*32 + lg*8];
                acc[0][nf] = __builtin_amdgcn_mfma_f32_16x16x32_bf16(a0, b, acc[0][nf], 0, 0, 0);
                acc[1][nf] = __builtin_amdgcn_mfma_f32_16x16x32_bf16(a1, b, acc[1][nf], 0, 0, 0);
            }
        }
#pragma unroll
        for (int nf = 0; nf < 4; nf++) {
            float bb = b1[(q*4+nf)*16 + lr];
#pragma unroll
            for (int rt = 0; rt < 2; rt++)
#pragma unroll
                for (int rr = 0; rr < 4; rr++) {
                    float hv = acc[rt][nf][rr] + bb;
                    float gl = 0.5f*hv*(1.f + erff(hv*0.70710678118f));
                    hT[(rt*64 + wtb + lg*4 + rr)*72 + nf*16 + lr] = f2bf(gl);
                }
        }
        FENCE();   // wave-private rows

        // stage 2: accumulate out += H_q @ W2[:, q]^T
#pragma unroll
        for (int kst2 = 0; kst2 < 2; kst2++) {
            bf16x8 a0 = *(const bf16x8*)&hT[(wtb+lr)*72 + kst2*32 + lg*8];
            bf16x8 a1 = *(const bf16x8*)&hT[(64+wtb+lr)*72 + kst2*32 + lg*8];
#pragma unroll
            for (int nf = 0; nf < 8; nf++) {
                bf16x8 b = *(const bf16x8*)&w2p[(nf*16+lr)*256 + q*64 + kst2*32 + lg*8];
                oacc[0][nf] = __builtin_amdgcn_mfma_f32_16x16x32_bf16(a0, b, oacc[0][nf], 0, 0, 0);
                oacc[1][nf] = __builtin_amdgcn_mfma_f32_16x16x32_bf16(a1, b, oacc[1][nf], 0, 0, 0);
            }
        }
        FENCE();   // hT reads complete before next quarter overwrites
    }

#pragma unroll
    for (int nf = 0; nf < 8; nf++) {
        float bb = b2[nf*16 + lr];
#pragma unroll
        for (int rt = 0; rt < 2; rt++)
#pragma unroll
            for (int rr = 0; rr < 4; rr++) {
                int idx = (base + rt*64 + wtb + lg*4 + rr)*128 + nf*16 + lr;
                z[idx] = z[idx] + oacc[rt][nf][rr] + bb;
            }
    }
}

// ---------------- kernel 8: final LN + transpose to (128,256,256) -----------
__global__ __launch_bounds__(256) void k_post(
    const float* __restrict__ z2,
    const float* __restrict__ g, const float* __restrict__ b,
    float* __restrict__ out)
{
    __shared__ float buf[64][129];
    const int blk = blockIdx.x;           // h*4 + quarter
    const int h = blk >> 2, w0 = (blk & 3)*64;
    const int tid = threadIdx.x;
    const int t = tid >> 2, part = tid & 3;

    const float* zr = z2 + (h*256 + w0 + t)*128 + part*32;
    float r[32]; float s1 = 0.f, s2 = 0.f;
#pragma unroll
    for (int k4 = 0; k4 < 8; k4++) {
        float4 v = *(const float4*)&zr[k4*4];
        r[k4*4+0]=v.x; r[k4*4+1]=v.y; r[k4*4+2]=v.z; r[k4*4+3]=v.w;
        s1 += v.x+v.y+v.z+v.w;
        s2 += v.x*v.x+v.y*v.y+v.z*v.z+v.w*v.w;
    }
    s1 += __shfl_xor(s1, 1); s1 += __shfl_xor(s1, 2);
    s2 += __shfl_xor(s2, 1); s2 += __shfl_xor(s2, 2);
    const float mean = s1*(1.f/128.f);
    const float var  = s2*(1.f/128.f) - mean*mean;
    const float rstd = rsqrtf(var + LN_EPS);
#pragma unroll
    for (int k = 0; k < 32; k++) {
        int c = part*32 + k;
        buf[t][c] = (r[k]-mean)*rstd*g[c] + b[c];
    }
    __syncthreads();
    for (int idx = tid; idx < 64*128; idx += 256) {
        int c = idx >> 6, wl = idx & 63;
        out[(c*256 + h)*256 + w0 + wl] = buf[wl][c];
    }
}

// ============================================================================
extern "C" void kernel_launch(void* const* d_in, const int* in_sizes, int n_in,
                              void* d_out, int out_size, void* d_ws, size_t ws_size,
                              hipStream_t stream)
{
    (void)in_sizes; (void)n_in; (void)out_size; (void)ws_size;
    const float* x       = (const float*)d_in[1];
    const float* feature = (const float*)d_in[2];
    const float* I_inv   = (const float*)d_in[3];
    const float* E_inv   = (const float*)d_in[4];
    const float* fl_g = (const float*)d_in[5],  *fl_b = (const float*)d_in[6];
    const float* fl_m = (const float*)d_in[7],  *fl_v = (const float*)d_in[8];
    const float* fl_w = (const float*)d_in[9];
    const float* fp_g = (const float*)d_in[10], *fp_b = (const float*)d_in[11];
    const float* fp_m = (const float*)d_in[12], *fp_v = (const float*)d_in[13];
    const float* fp_w = (const float*)d_in[14];
    const float* bev_w = (const float*)d_in[15], *bev_b = (const float*)d_in[16];
    const float* img_w = (const float*)d_in[17], *cam_w = (const float*)d_in[18];
    const float* a1_nq_g = (const float*)d_in[19], *a1_nq_b = (const float*)d_in[20];
    const float* a1_wq = (const float*)d_in[21], *a1_bq = (const float*)d_in[22];
    const float* a1_nk_g = (const float*)d_in[23], *a1_nk_b = (const float*)d_in[24];
    const float* a1_wk = (const float*)d_in[25], *a1_bk = (const float*)d_in[26];
    const float* a1_nv_g = (const float*)d_in[27], *a1_nv_b = (const float*)d_in[28];
    const float* a1_wv = (const float*)d_in[29], *a1_bv = (const float*)d_in[30];
    const float* a1_wp = (const float*)d_in[31], *a1_bp = (const float*)d_in[32];
    const float* pn1_g = (const float*)d_in[33], *pn1_b = (const float*)d_in[34];
    const float* m1_w1 = (const float*)d_in[35], *m1_b1 = (const float*)d_in[36];
    const float* m1_w2 = (const float*)d_in[37], *m1_b2 = (const float*)d_in[38];
    const float* a2_nq_g = (const float*)d_in[39], *a2_nq_b = (const float*)d_in[40];
    const float* a2_wq = (const float*)d_in[41], *a2_bq = (const float*)d_in[42];
    const float* a2_nk_g = (const float*)d_in[43], *a2_nk_b = (const float*)d_in[44];
    const float* a2_wk = (const float*)d_in[45], *a2_bk = (const float*)d_in[46];
    const float* a2_nv_g = (const float*)d_in[47], *a2_nv_b = (const float*)d_in[48];
    const float* a2_wv = (const float*)d_in[49], *a2_bv = (const float*)d_in[50];
    const float* a2_wp = (const float*)d_in[51], *a2_bp = (const float*)d_in[52];
    const float* pn2_g = (const float*)d_in[53], *pn2_b = (const float*)d_in[54];
    const float* m2_w1 = (const float*)d_in[55], *m2_b1 = (const float*)d_in[56];
    const float* m2_w2 = (const float*)d_in[57], *m2_b2 = (const float*)d_in[58];
    const float* post_g = (const float*)d_in[59], *post_b = (const float*)d_in[60];

    float* ws  = (float*)d_ws;
    unsigned short* pk = (unsigned short*)ws;
    const unsigned short* wp1p  = pk + 16384;
    const unsigned short* wp2p  = pk + 49152;
    const unsigned short* m1w1p = pk + 65536;
    const unsigned short* m1w2p = pk + 98304;
    const unsigned short* m2w1p = pk + 131072;
    const unsigned short* m2w2p = pk + 163840;
    const unsigned short* fpwp  = pk + 196608;
    const unsigned short* flwp  = pk + 212992;
    const unsigned short* wk1p  = pk + 229376;
    const unsigned short* wv1p  = pk + 245760;
    const unsigned short* wk2p  = pk + 262144;
    const unsigned short* wv2p  = pk + 278528;
    const unsigned short* wq1Tp = pk + 294912;
    const unsigned short* wq2Tp = pk + 311296;

    float* cb  = ws + 163840;                       // [4][128]
    float* Mb1 = ws + 164352;                       // [256][64]
    float* Mb2 = ws + 180736;
    float* kp2 = ws + 197120;                       // live through mwin
    float* vp2 = ws + 721408;                       // live through attn2
    unsigned short* Mw2 = (unsigned short*)(ws + 1245696);  // ends 2294272
    float* kp1 = ws + 2294272;                      // dead after mwin
    float* vp1 = ws + 2818560;                      // dead after attn1
    unsigned short* Mw1 = (unsigned short*)(ws + 3342848);  // ends 4391424
    float* key = ws + 3342848;                      // aliases Mw1 (dead first)
    float* val = ws + 3867136;
    float* img = ws + 4391424;
    float* z2  = ws + 2294272;                      // overlaps dead kp1..img
    float* z1  = (float*)d_out;

    k_pack<<<1283, 256, 0, stream>>>(pk, cb,
        a1_wq, a1_wp, a2_wq, a2_wp, m1_w1, m1_w2, m2_w1, m2_w2,
        fp_w, fl_w, a1_wk, a1_wv, a2_wk, a2_wv, bev_b, cam_w, E_inv);
    k_img_embed<<<4096, 128, 0, stream>>>(I_inv, E_inv, img_w, cam_w, img);
    k_keyval<<<64, 256, 0, stream>>>(feature, img,
                                     fp_g, fp_b, fp_m, fp_v, fpwp,
                                     fl_g, fl_b, fl_m, fl_v, flwp,
                                     key, val);
    k_kvproj<<<256, 256, 0, stream>>>(key, val,
                                      a1_nk_g, a1_nk_b, wk1p, a1_bk,
                                      a1_nv_g, a1_nv_b, wv1p, a1_bv,
                                      a2_nk_g, a2_nk_b, wk2p, a2_bk,
                                      a2_nv_g, a2_nv_b, wv2p, a2_bv,
                                      kp1, vp1, kp2, vp2);
    k_mwin<<<512, 256, 0, stream>>>(kp1, kp2, wq1Tp, wq2Tp, a1_bq, a2_bq,
                                    Mw1, Mw2, Mb1, Mb2);
    k_attn1<<<1024, 256, 0, stream>>>(x, vp1, Mw1, Mb1, bev_w, cb,
                                      a1_nq_g, a1_nq_b, wp1p, a1_bp, z1);
    k_mlp<<<512, 256, 0, stream>>>(z1, pn1_g, pn1_b, m1w1p, m1_b1, m1w2p, m1_b2);
    k_attn2<<<1024, 256, 0, stream>>>(z1, vp2, Mw2, Mb2,
                                      a2_nq_g, a2_nq_b, wp2p, a2_bp, z2);
    k_mlp<<<512, 256, 0, stream>>>(z2, pn2_g, pn2_b, m2w1p, m2_b1, m2w2p, m2_b2);
    k_post<<<1024, 256, 0, stream>>>(z2, post_g, post_b, (float*)d_out);
}

// Round 23
// 391.088 us; speedup vs baseline: 1.1301x; 1.1301x over previous
//
#include <hip/hip_runtime.h>
#include <math.h>

#define LN_EPS 1e-5f
#define BN_EPS 1e-5f
#define QK_SCALE 0.1767766953f

typedef __attribute__((ext_vector_type(8))) short bf16x8;
typedef __attribute__((ext_vector_type(4))) float f32x4;

__device__ __forceinline__ unsigned short f2bf(float x) {
    union { float f; unsigned u; } v; v.f = x;
    unsigned r = v.u + 0x7FFFu + ((v.u >> 16) & 1u);
    return (unsigned short)(r >> 16);
}
__device__ __forceinline__ float bf2f(unsigned short h) {
    union { unsigned u; float f; } v; v.u = ((unsigned)h) << 16;
    return v.f;
}
__device__ __forceinline__ unsigned packbf(float a, float b) {
    return (unsigned)f2bf(a) | ((unsigned)f2bf(b) << 16);
}
#define FENCE() asm volatile("" ::: "memory")

// ============================================================================
// B=1, N=4, DIM=FDIM=128, H=W=256, FH=FW=32, QW 16x16, FW 2x2, HEADS=4, DH=32
// token-major activations: [(n*1024+p)*128 + c]
// ROUND-19 GREEN KERNEL VERBATIM (392us, absmax 0.03125, post-timing clean).
// r20 (mlp big-tile: occupancy regression), r21 (mlp cross-wave: wrong),
// r22 (attn2 Mw-staging: replay-divergent) are all quarantined. This locks
// the best proven state.
// ============================================================================

// ---------------- kernel 0: pack weights to bf16 (+transposed wq) + cb ------
__global__ void k_pack(unsigned short* __restrict__ dst, float* __restrict__ cb,
    const float* wq1, const float* wp1, const float* wq2, const float* wp2,
    const float* m1w1, const float* m1w2, const float* m2w1, const float* m2w2,
    const float* fpw, const float* flw,
    const float* wk1, const float* wv1, const float* wk2, const float* wv2,
    const float* bev_b, const float* cam_w, const float* E_inv)
{
    int gid = blockIdx.x * 256 + threadIdx.x;
    if (gid < 294912) {
        const float* src; int off = gid;
        if      (off < 16384)  { src = wq1; }
        else if (off < 32768)  { src = wp1;  off -= 16384; }
        else if (off < 49152)  { src = wq2;  off -= 32768; }
        else if (off < 65536)  { src = wp2;  off -= 49152; }
        else if (off < 98304)  { src = m1w1; off -= 65536; }
        else if (off < 131072) { src = m1w2; off -= 98304; }
        else if (off < 163840) { src = m2w1; off -= 131072; }
        else if (off < 196608) { src = m2w2; off -= 163840; }
        else if (off < 212992) { src = fpw;  off -= 196608; }
        else if (off < 229376) { src = flw;  off -= 212992; }
        else if (off < 245760) { src = wk1;  off -= 229376; }
        else if (off < 262144) { src = wv1;  off -= 245760; }
        else if (off < 278528) { src = wk2;  off -= 262144; }
        else                   { src = wv2;  off -= 278528; }
        dst[gid] = f2bf(src[off]);
    } else if (gid < 311296) {
        int off = gid - 294912;                    // wq1^T: [in][out]
        dst[gid] = f2bf(wq1[(off & 127)*128 + (off >> 7)]);
    } else if (gid < 327680) {
        int off = gid - 311296;                    // wq2^T
        dst[gid] = f2bf(wq2[(off & 127)*128 + (off >> 7)]);
    } else if (gid < 328192) {
        int i = gid - 327680;
        int n = i >> 7, c = i & 127;
        const float* Ev = E_inv + n * 16;
        cb[i] = bev_b[c] - (cam_w[c*4+0]*Ev[3] + cam_w[c*4+1]*Ev[7]
                          + cam_w[c*4+2]*Ev[11] + cam_w[c*4+3]*Ev[15]);
    }
}

// ---------------- kernel 1: img_embed, token-major --------------------------
__global__ void k_img_embed(const float* __restrict__ I_inv,
                            const float* __restrict__ E_inv,
                            const float* __restrict__ img_w,
                            const float* __restrict__ cam_w,
                            float* __restrict__ img_embed)
{
    const int blk = blockIdx.x;          // n*1024 + p, p = fy*32+fx
    const int n = blk >> 10, p = blk & 1023;
    const int fy = p >> 5, fx = p & 31;
    const float px = fx * (256.0f / 31.0f);
    const float py = fy * (256.0f / 31.0f);
    const float* Iv = I_inv + n * 9;
    const float* Ev = E_inv + n * 16;
    const float c0 = Iv[0]*px + Iv[1]*py + Iv[2];
    const float c1 = Iv[3]*px + Iv[4]*py + Iv[5];
    const float c2 = Iv[6]*px + Iv[7]*py + Iv[8];
    const float d0 = Ev[0]*c0 + Ev[1]*c1 + Ev[2]*c2 + Ev[3];
    const float d1 = Ev[4]*c0 + Ev[5]*c1 + Ev[6]*c2 + Ev[7];
    const float d2 = Ev[8]*c0 + Ev[9]*c1 + Ev[10]*c2 + Ev[11];
    const float d3 = Ev[12]*c0 + Ev[13]*c1 + Ev[14]*c2 + Ev[15];
    const int c = threadIdx.x;
    const float ce = cam_w[c*4+0]*Ev[3] + cam_w[c*4+1]*Ev[7]
                   + cam_w[c*4+2]*Ev[11] + cam_w[c*4+3]*Ev[15];
    float v = img_w[c*4+0]*d0 + img_w[c*4+1]*d1
            + img_w[c*4+2]*d2 + img_w[c*4+3]*d3 - ce;
    __shared__ float red[128];
    red[c] = v * v;
    __syncthreads();
    for (int s = 64; s > 0; s >>= 1) {
        if (c < s) red[c] += red[c + s];
        __syncthreads();
    }
    img_embed[(n*1024 + p)*128 + c] = v / (sqrtf(red[0]) + 1e-7f);
}

// ---------------- kernel 2: key/val = BN+ReLU + MFMA 1x1 conv ---------------
__global__ __launch_bounds__(256) void k_keyval(
    const float* __restrict__ feature,
    const float* __restrict__ img_embed,
    const float* __restrict__ fp_g, const float* __restrict__ fp_b,
    const float* __restrict__ fp_m, const float* __restrict__ fp_v,
    const unsigned short* __restrict__ fpw,
    const float* __restrict__ fl_g, const float* __restrict__ fl_b,
    const float* __restrict__ fl_m, const float* __restrict__ fl_v,
    const unsigned short* __restrict__ flw,
    float* __restrict__ key, float* __restrict__ val)
{
    __shared__ __align__(16) unsigned short aP[64*136];
    __shared__ __align__(16) unsigned short aL[64*136];
    const int n = blockIdx.x >> 4, p0 = (blockIdx.x & 15) * 64;
    const int tid = threadIdx.x;

    for (int idx = tid; idx < 8192; idx += 256) {
        int c = idx >> 6, dt = idx & 63;
        float f = feature[(n*128 + c)*1024 + p0 + dt];
        float xp = (f - fp_m[c]) * rsqrtf(fp_v[c] + BN_EPS) * fp_g[c] + fp_b[c];
        float xl = (f - fl_m[c]) * rsqrtf(fl_v[c] + BN_EPS) * fl_g[c] + fl_b[c];
        aP[dt*136 + c] = f2bf(fmaxf(xp, 0.f));
        aL[dt*136 + c] = f2bf(fmaxf(xl, 0.f));
    }
    __syncthreads();

    const int lane = tid & 63, wid = tid >> 6;
    const int lr = lane & 15, lg = lane >> 4;
    const int wtb = wid * 16;
    f32x4 ak[8], av[8];
    const f32x4 z4 = {0.f, 0.f, 0.f, 0.f};
#pragma unroll
    for (int nf = 0; nf < 8; nf++) { ak[nf] = z4; av[nf] = z4; }
#pragma unroll
    for (int kst = 0; kst < 4; kst++) {
        bf16x8 a1 = *(const bf16x8*)&aP[(wtb+lr)*136 + kst*32 + lg*8];
        bf16x8 a2 = *(const bf16x8*)&aL[(wtb+lr)*136 + kst*32 + lg*8];
#pragma unroll
        for (int nf = 0; nf < 8; nf++) {
            bf16x8 bK = *(const bf16x8*)&fpw[(nf*16+lr)*128 + kst*32 + lg*8];
            bf16x8 bV = *(const bf16x8*)&flw[(nf*16+lr)*128 + kst*32 + lg*8];
            ak[nf] = __builtin_amdgcn_mfma_f32_16x16x32_bf16(a1, bK, ak[nf], 0, 0, 0);
            av[nf] = __builtin_amdgcn_mfma_f32_16x16x32_bf16(a2, bV, av[nf], 0, 0, 0);
        }
    }
#pragma unroll
    for (int nf = 0; nf < 8; nf++) {
#pragma unroll
        for (int rr = 0; rr < 4; rr++) {
            int g = (n*1024 + p0 + wtb + lg*4 + rr)*128 + nf*16 + lr;
            key[g] = ak[nf][rr] + img_embed[g];
            val[g] = av[nf][rr];
        }
    }
}

// ---------------- kernel 3: k/v LN + MFMA projection (grid 256, 1 proj/blk) -
__global__ __launch_bounds__(256) void k_kvproj(
    const float* __restrict__ key, const float* __restrict__ val,
    const float* __restrict__ k1g, const float* __restrict__ k1b,
    const unsigned short* __restrict__ wk1, const float* __restrict__ bk1,
    const float* __restrict__ v1g, const float* __restrict__ v1b,
    const unsigned short* __restrict__ wv1, const float* __restrict__ bv1,
    const float* __restrict__ k2g, const float* __restrict__ k2b,
    const unsigned short* __restrict__ wk2, const float* __restrict__ bk2,
    const float* __restrict__ v2g, const float* __restrict__ v2b,
    const unsigned short* __restrict__ wv2, const float* __restrict__ bv2,
    float* __restrict__ kp1, float* __restrict__ vp1,
    float* __restrict__ kp2, float* __restrict__ vp2)
{
    __shared__ __align__(16) unsigned short tile[64*136];
    const int pj = blockIdx.x >> 6;            // 0:k1 1:v1 2:k2 3:v2
    const int tok0 = (blockIdx.x & 63) * 64;
    const int tid = threadIdx.x;
    const int t = tid >> 2, part = tid & 3;

    const float* gsel[4] = {k1g, v1g, k2g, v2g};
    const float* asel[4] = {k1b, v1b, k2b, v2b};
    const unsigned short* wsel[4] = {wk1, wv1, wk2, wv2};
    const float* bsel[4] = {bk1, bv1, bk2, bv2};
    float* osel[4] = {kp1, vp1, kp2, vp2};
    const float* src = (pj & 1) ? val : key;
    const float* g  = gsel[pj];
    const float* ba = asel[pj];

    float rr_[32];
    float s1 = 0.f, s2 = 0.f;
#pragma unroll
    for (int k4 = 0; k4 < 8; k4++) {
        float4 a = *(const float4*)&src[(tok0+t)*128 + part*32 + k4*4];
        rr_[k4*4+0]=a.x; rr_[k4*4+1]=a.y; rr_[k4*4+2]=a.z; rr_[k4*4+3]=a.w;
        s1 += a.x+a.y+a.z+a.w; s2 += a.x*a.x+a.y*a.y+a.z*a.z+a.w*a.w;
    }
    s1 += __shfl_xor(s1, 1); s1 += __shfl_xor(s1, 2);
    s2 += __shfl_xor(s2, 1); s2 += __shfl_xor(s2, 2);
    const float mean = s1*(1.f/128.f);
    const float var  = s2*(1.f/128.f) - mean*mean;
    const float rstd = rsqrtf(var + LN_EPS);
#pragma unroll
    for (int k = 0; k < 32; k++) {
        int c = part*32 + k;
        float hat = (rr_[k]-mean)*rstd;
        tile[t*136 + c] = f2bf(hat*g[c] + ba[c]);
    }
    FENCE();   // wave-private rows

    const int lane = tid & 63, wid = tid >> 6;
    const int lr = lane & 15, lg = lane >> 4;
    const int wtb = wid * 16;
    const unsigned short* wp_ = wsel[pj];
    const f32x4 z4 = {0.f, 0.f, 0.f, 0.f};
    f32x4 acc[8];
#pragma unroll
    for (int nf = 0; nf < 8; nf++) acc[nf] = z4;
#pragma unroll
    for (int kst = 0; kst < 4; kst++) {
        bf16x8 a = *(const bf16x8*)&tile[(wtb+lr)*136 + kst*32 + lg*8];
#pragma unroll
        for (int nf = 0; nf < 8; nf++) {
            bf16x8 b = *(const bf16x8*)&wp_[(nf*16+lr)*128 + kst*32 + lg*8];
            acc[nf] = __builtin_amdgcn_mfma_f32_16x16x32_bf16(a, b, acc[nf], 0, 0, 0);
        }
    }
    float* outp = osel[pj];
#pragma unroll
    for (int nf = 0; nf < 8; nf++) {
        float bb = bsel[pj][nf*16 + lr];
#pragma unroll
        for (int rr2 = 0; rr2 < 4; rr2++)
            outp[(tok0 + wtb + lg*4 + rr2)*128 + nf*16 + lr] = acc[nf][rr2] + bb;
    }
}

// ---------------- kernel 3.5: per-window M = scale*(K @ Wq_hd), Mb ----------
__global__ __launch_bounds__(256) void k_mwin(
    const float* __restrict__ kp1, const float* __restrict__ kp2,
    const unsigned short* __restrict__ wq1T, const unsigned short* __restrict__ wq2T,
    const float* __restrict__ bq1, const float* __restrict__ bq2,
    unsigned short* __restrict__ Mw1, unsigned short* __restrict__ Mw2,
    float* __restrict__ Mb1, float* __restrict__ Mb2)
{
    __shared__ __align__(16) unsigned short kt[16*136];
    const int blk = blockIdx.x;
    const int stage = blk >> 8, win = blk & 255;
    const int wx = win >> 4, wy = win & 15;
    const int tid = threadIdx.x;

    const float* kp = stage ? kp2 : kp1;
    const unsigned short* wqT = stage ? wq2T : wq1T;
    const float* bq = stage ? bq2 : bq1;
    unsigned short* Mw = stage ? Mw2 : Mw1;
    float* Mb = stage ? Mb2 : Mb1;

    for (int idx = tid; idx < 2048; idx += 256) {
        int c = idx & 127, j = idx >> 7;
        int nk = j >> 2, f1 = (j >> 1) & 1, f2 = j & 1;
        int tok = stage ? (nk*1024 + (f1*16+wx)*32 + (f2*16+wy))
                        : (nk*1024 + (wx*2+f1)*32 + (wy*2+f2));
        kt[j*136 + c] = f2bf(kp[tok*128 + c]);
    }
    __syncthreads();

    const int lane = tid & 63, wid = tid >> 6;
    const int lr = lane & 15, lg = lane >> 4;
    const f32x4 z4 = {0.f, 0.f, 0.f, 0.f};
#pragma unroll
    for (int cc = 0; cc < 2; cc++) {
        int ct = wid*2 + cc;
#pragma unroll
        for (int hd = 0; hd < 4; hd++) {
            bf16x8 a = *(const bf16x8*)&kt[lr*136 + hd*32 + lg*8];
            bf16x8 b = *(const bf16x8*)&wqT[(ct*16+lr)*128 + hd*32 + lg*8];
            f32x4 acc = __builtin_amdgcn_mfma_f32_16x16x32_bf16(a, b, z4, 0, 0, 0);
#pragma unroll
            for (int rr = 0; rr < 4; rr++)
                Mw[((win*4 + hd)*16 + lg*4 + rr)*128 + ct*16 + lr]
                    = f2bf(acc[rr] * QK_SCALE);
        }
    }
    if (tid < 64) {
        int hd = tid >> 4, ky = tid & 15;
        float s = 0.f;
        for (int d = 0; d < 32; d++)
            s += bq[hd*32 + d] * bf2f(kt[ky*136 + hd*32 + d]);
        Mb[win*64 + tid] = s * QK_SCALE;
    }
}

// ---------------- kernel 4: stage-1 attention, hoisted/LDS-staged qgen ------
__global__ __launch_bounds__(256) void k_attn1(
    const float* __restrict__ x,
    const float* __restrict__ vp,
    const unsigned short* __restrict__ mw, const float* __restrict__ mb,
    const float* __restrict__ bev_w, const float* __restrict__ cb,
    const float* __restrict__ nqg, const float* __restrict__ nqb,
    const unsigned short* __restrict__ wpp, const float* __restrict__ bp,
    float* __restrict__ z1)
{
    __shared__ __align__(16) unsigned short aT[64*136];
    __shared__ __align__(16) unsigned short mws[64*136];    // staged Mw window
    __shared__ __align__(16) unsigned short vbT[128*24];
    __shared__ __align__(16) unsigned short xbuf[64*132];   // bf16 residual
    __shared__ float mbs[64];
    __shared__ float cbs[512];                              // [4][128] cb
    __shared__ float nqgs[128];
    __shared__ float nqbs[128];

    const int blk = blockIdx.x;
    const int win = blk >> 2, rg = blk & 3;
    const int wx = win >> 4, wy = win & 15;
    const int tid = threadIdx.x;
    const int lane = tid & 63, wid = tid >> 6;
    const int lr = lane & 15, lg = lane >> 4;
    const int wtb = wid * 16;

    // V^T tile (bf16) for PV B-frags
    for (int idx = tid; idx < 2048; idx += 256) {
        int c = idx & 127, j = idx >> 7;
        int nk = j >> 2, f1 = (j >> 1) & 1, f2 = j & 1;
        int src = (nk*1024 + (wx*2+f1)*32 + (wy*2+f2))*128 + c;
        vbT[c*24 + j] = f2bf(vp[src]);
    }
    // stage the window's Mw tile (4 heads x 16 keys x 128) coalesced, bit-exact
    {
        const unsigned short* mwsrc = mw + win*8192;
        for (int idx = tid; idx < 2048; idx += 256) {
            int row = idx >> 5, c4 = (idx & 31)*4;
            *(ushort4*)&mws[row*136 + c4] = *(const ushort4*)&mwsrc[row*128 + c4];
        }
    }
    // coalesced bf16 x staging (residual only; r10-proven)
    for (int idx = tid; idx < 8192; idx += 256) {
        int tt = idx & 63, c = idx >> 6;
        int hh = wx*16 + rg*4 + (tt >> 4), ww = wy*16 + (tt & 15);
        xbuf[tt*132 + c] = f2bf(x[c*65536 + hh*256 + ww]);
    }
    if (tid < 64) mbs[tid] = mb[win*64 + tid];
    // stage small per-view tables (bit-exact values)
    for (int idx = tid; idx < 512; idx += 256) cbs[idx] = cb[idx];
    if (tid < 128) { nqgs[tid] = nqg[tid]; nqbs[tid] = nqb[tid]; }

    const int t = tid >> 2, part = tid & 3;
    const int w1 = rg*4 + (t >> 4), w2 = t & 15;
    const int h = wx*16 + w1, w = wy*16 + w2;
    const float world0 = 50.f - (float)h * (100.f/255.f);
    const float world1 = 50.f - (float)w * (100.f/255.f);

    // qgen xv: direct global f32 read, (t,part) mapping (4 full lines/instr)
    float xv[32];
#pragma unroll
    for (int k = 0; k < 32; k++) xv[k] = x[(part*32+k)*65536 + h*256 + w];
    // hoisted view-invariant bev_w dot (read once, not 4x)
    float base_[32];
#pragma unroll
    for (int k = 0; k < 32; k++) {
        int c = part*32 + k;
        base_[k] = bev_w[c*2+0]*world0 + bev_w[c*2+1]*world1;
    }
    __syncthreads();    // the ONLY barrier (vbT/mws/xbuf/mbs/cbs/nqgs/nqbs)

    f32x4 aacc[4][2];
    const f32x4 z4 = {0.f, 0.f, 0.f, 0.f};
#pragma unroll
    for (int hd = 0; hd < 4; hd++) { aacc[hd][0] = z4; aacc[hd][1] = z4; }

    uint2 pa[4], pb[4];

    // per-view: qgen -> aT (wave-private rows), scores via LDS mws, softmax
    auto do_view = [&](int n, uint2* pp) {
        float r[32]; float ss = 0.f;
#pragma unroll
        for (int k = 0; k < 32; k++) {
            int c = part*32 + k;
            float e = base_[k] + cbs[n*128 + c];
            r[k] = e; ss += e*e;
        }
        ss += __shfl_xor(ss, 1); ss += __shfl_xor(ss, 2);
        const float invn = 1.f / (sqrtf(ss) + 1e-7f);
        float s1 = 0.f, s2 = 0.f;
#pragma unroll
        for (int k = 0; k < 32; k++) {
            float qv = r[k]*invn + xv[k];
            r[k] = qv; s1 += qv; s2 += qv*qv;
        }
        s1 += __shfl_xor(s1, 1); s1 += __shfl_xor(s1, 2);
        s2 += __shfl_xor(s2, 1); s2 += __shfl_xor(s2, 2);
        const float mean = s1*(1.f/128.f);
        const float var  = s2*(1.f/128.f) - mean*mean;
        const float rstd = rsqrtf(var + LN_EPS);
#pragma unroll
        for (int k4 = 0; k4 < 8; k4++) {
            int c = part*32 + k4*4;
            ushort4 u;
            u.x = f2bf((r[k4*4+0]-mean)*rstd*nqgs[c+0] + nqbs[c+0]);
            u.y = f2bf((r[k4*4+1]-mean)*rstd*nqgs[c+1] + nqbs[c+1]);
            u.z = f2bf((r[k4*4+2]-mean)*rstd*nqgs[c+2] + nqbs[c+2]);
            u.w = f2bf((r[k4*4+3]-mean)*rstd*nqgs[c+3] + nqbs[c+3]);
            *(ushort4*)&aT[t*136 + c] = u;
        }
        FENCE();

        f32x4 sacc[4];
#pragma unroll
        for (int hd = 0; hd < 4; hd++) sacc[hd] = z4;
#pragma unroll
        for (int kst = 0; kst < 4; kst++) {
            bf16x8 bq_ = *(const bf16x8*)&aT[(wtb+lr)*136 + kst*32 + lg*8];
#pragma unroll
            for (int hd = 0; hd < 4; hd++) {
                bf16x8 am = *(const bf16x8*)&mws[(hd*16 + lr)*136 + kst*32 + lg*8];
                sacc[hd] = __builtin_amdgcn_mfma_f32_16x16x32_bf16(am, bq_, sacc[hd], 0, 0, 0);
            }
        }
#pragma unroll
        for (int hd = 0; hd < 4; hd++) {
            float e0 = sacc[hd][0] + mbs[hd*16 + lg*4 + 0];
            float e1 = sacc[hd][1] + mbs[hd*16 + lg*4 + 1];
            float e2 = sacc[hd][2] + mbs[hd*16 + lg*4 + 2];
            float e3 = sacc[hd][3] + mbs[hd*16 + lg*4 + 3];
            float mx = fmaxf(fmaxf(e0, e1), fmaxf(e2, e3));
            mx = fmaxf(mx, __shfl_xor(mx, 16));
            mx = fmaxf(mx, __shfl_xor(mx, 32));
            e0 = __expf(e0-mx); e1 = __expf(e1-mx);
            e2 = __expf(e2-mx); e3 = __expf(e3-mx);
            float sum = e0+e1+e2+e3;
            sum += __shfl_xor(sum, 16);
            sum += __shfl_xor(sum, 32);
            float is = 1.f/sum;
            pp[hd] = make_uint2(packbf(e0*is, e1*is), packbf(e2*is, e3*is));
        }
        FENCE();
    };

    // PV for a view pair: K=32 = [viewA 16 keys | viewB 16 keys], B=[V;V]
    auto pv_pair = [&]() {
        const int s0 = (lg & 1)*32 + lr;
        const int s1 = s0 + 16;
        const bool hi = (lg >> 1) != 0;
#pragma unroll
        for (int hd = 0; hd < 4; hd++) {
            unsigned a00 = __shfl(pa[hd].x, s0), a01 = __shfl(pa[hd].y, s0);
            unsigned a10 = __shfl(pa[hd].x, s1), a11 = __shfl(pa[hd].y, s1);
            unsigned b00 = __shfl(pb[hd].x, s0), b01 = __shfl(pb[hd].y, s0);
            unsigned b10 = __shfl(pb[hd].x, s1), b11 = __shfl(pb[hd].y, s1);
            union { unsigned u[4]; bf16x8 v; } af;
            af.u[0] = hi ? b00 : a00; af.u[1] = hi ? b01 : a01;
            af.u[2] = hi ? b10 : a10; af.u[3] = hi ? b11 : a11;
#pragma unroll
            for (int dt = 0; dt < 2; dt++) {
                bf16x8 bv = *(const bf16x8*)&vbT[(hd*32+dt*16+lr)*24 + (lg&1)*8];
                aacc[hd][dt] = __builtin_amdgcn_mfma_f32_16x16x32_bf16(af.v, bv, aacc[hd][dt], 0, 0, 0);
            }
        }
    };

    do_view(0, pa); do_view(1, pb); pv_pair();
    do_view(2, pa); do_view(3, pb); pv_pair();

    // view-mean att -> aT (wave-private rows)
#pragma unroll
    for (int hd = 0; hd < 4; hd++)
#pragma unroll
        for (int dt = 0; dt < 2; dt++)
#pragma unroll
            for (int rr = 0; rr < 4; rr++)
                aT[(wtb + lg*4 + rr)*136 + hd*32 + dt*16 + lr]
                    = f2bf(aacc[hd][dt][rr] * 0.25f);
    FENCE();

    // out-projection + residual (bf16 from xbuf, r10-proven)
    f32x4 acc[8];
#pragma unroll
    for (int nf = 0; nf < 8; nf++) acc[nf] = z4;
#pragma unroll
    for (int kst = 0; kst < 4; kst++) {
        bf16x8 a = *(const bf16x8*)&aT[(wtb+lr)*136 + kst*32 + lg*8];
#pragma unroll
        for (int nf = 0; nf < 8; nf++) {
            bf16x8 b = *(const bf16x8*)&wpp[(nf*16+lr)*128 + kst*32 + lg*8];
            acc[nf] = __builtin_amdgcn_mfma_f32_16x16x32_bf16(a, b, acc[nf], 0, 0, 0);
        }
    }
#pragma unroll
    for (int nf = 0; nf < 8; nf++) {
        float bpv = bp[nf*16 + lr];
#pragma unroll
        for (int rr = 0; rr < 4; rr++) {
            int tt = wtb + lg*4 + rr;
            int hh = wx*16 + rg*4 + (tt >> 4), ww = wy*16 + (tt & 15);
            float res = bf2f(xbuf[tt*132 + nf*16 + lr]);
            z1[(hh*256+ww)*128 + nf*16 + lr] = acc[nf][rr] + bpv + res;
        }
    }
}

// ---------------- kernel 6: stage-2 attention, 1 barrier --------------------
__global__ __launch_bounds__(256) void k_attn2(
    const float* __restrict__ z1,
    const float* __restrict__ vp,
    const unsigned short* __restrict__ mw, const float* __restrict__ mb,
    const float* __restrict__ nqg, const float* __restrict__ nqb,
    const unsigned short* __restrict__ wpp, const float* __restrict__ bp,
    float* __restrict__ z2)
{
    __shared__ __align__(16) unsigned short aT[64*136];
    __shared__ __align__(16) unsigned short vbT[128*24];
    __shared__ float mbs[64];

    const int blk = blockIdx.x;
    const int win = blk >> 2, rg = blk & 3;
    const int wx = win >> 4, wy = win & 15;
    const int tid = threadIdx.x;
    const int lane = tid & 63, wid = tid >> 6;
    const int lr = lane & 15, lg = lane >> 4;
    const int wtb = wid * 16;

    for (int idx = tid; idx < 2048; idx += 256) {
        int c = idx & 127, j = idx >> 7;
        int nk = j >> 2, f1 = (j >> 1) & 1, f2 = j & 1;
        int src = (nk*1024 + (f1*16+wx)*32 + (f2*16+wy))*128 + c;
        vbT[c*24 + j] = f2bf(vp[src]);
    }
    if (tid < 64) mbs[tid] = mb[win*64 + tid];

    const int t = tid >> 2, part = tid & 3;
    const int w1 = rg*4 + (t >> 4), w2 = t & 15;
    const int h = wx*16 + w1, w = wy*16 + w2;
    const float* zr = z1 + (h*256 + w)*128 + part*32;

    float r[32]; float s1 = 0.f, s2 = 0.f;
#pragma unroll
    for (int k4 = 0; k4 < 8; k4++) {
        float4 v = *(const float4*)&zr[k4*4];
        r[k4*4+0]=v.x; r[k4*4+1]=v.y; r[k4*4+2]=v.z; r[k4*4+3]=v.w;
        s1 += v.x+v.y+v.z+v.w;
        s2 += v.x*v.x+v.y*v.y+v.z*v.z+v.w*v.w;
    }
    s1 += __shfl_xor(s1, 1); s1 += __shfl_xor(s1, 2);
    s2 += __shfl_xor(s2, 1); s2 += __shfl_xor(s2, 2);
    const float mean = s1*(1.f/128.f);
    const float var  = s2*(1.f/128.f) - mean*mean;
    const float rstd = rsqrtf(var + LN_EPS);
#pragma unroll
    for (int k4 = 0; k4 < 8; k4++) {
        int c = part*32 + k4*4;
        ushort4 u;
        u.x = f2bf((r[k4*4+0]-mean)*rstd*nqg[c+0] + nqb[c+0]);
        u.y = f2bf((r[k4*4+1]-mean)*rstd*nqg[c+1] + nqb[c+1]);
        u.z = f2bf((r[k4*4+2]-mean)*rstd*nqg[c+2] + nqb[c+2]);
        u.w = f2bf((r[k4*4+3]-mean)*rstd*nqg[c+3] + nqb[c+3]);
        *(ushort4*)&aT[t*136 + c] = u;
    }
    __syncthreads();    // the ONLY barrier (vbT/mbs)

    const f32x4 z4 = {0.f, 0.f, 0.f, 0.f};
    f32x4 sacc[4];
#pragma unroll
    for (int hd = 0; hd < 4; hd++) sacc[hd] = z4;
#pragma unroll
    for (int kst = 0; kst < 4; kst++) {
        bf16x8 bq_ = *(const bf16x8*)&aT[(wtb+lr)*136 + kst*32 + lg*8];
#pragma unroll
        for (int hd = 0; hd < 4; hd++) {
            bf16x8 am = *(const bf16x8*)&mw[((win*4+hd)*16 + lr)*128 + kst*32 + lg*8];
            sacc[hd] = __builtin_amdgcn_mfma_f32_16x16x32_bf16(am, bq_, sacc[hd], 0, 0, 0);
        }
    }
    uint2 pa[4];
#pragma unroll
    for (int hd = 0; hd < 4; hd++) {
        float e0 = sacc[hd][0] + mbs[hd*16 + lg*4 + 0];
        float e1 = sacc[hd][1] + mbs[hd*16 + lg*4 + 1];
        float e2 = sacc[hd][2] + mbs[hd*16 + lg*4 + 2];
        float e3 = sacc[hd][3] + mbs[hd*16 + lg*4 + 3];
        float mx = fmaxf(fmaxf(e0, e1), fmaxf(e2, e3));
        mx = fmaxf(mx, __shfl_xor(mx, 16));
        mx = fmaxf(mx, __shfl_xor(mx, 32));
        e0 = __expf(e0-mx); e1 = __expf(e1-mx);
        e2 = __expf(e2-mx); e3 = __expf(e3-mx);
        float sum = e0+e1+e2+e3;
        sum += __shfl_xor(sum, 16);
        sum += __shfl_xor(sum, 32);
        float is = 1.f/sum;
        pa[hd] = make_uint2(packbf(e0*is, e1*is), packbf(e2*is, e3*is));
    }

    // PV: single view, upper 16 k-slots zero
    f32x4 aacc[4][2];
#pragma unroll
    for (int hd = 0; hd < 4; hd++) { aacc[hd][0] = z4; aacc[hd][1] = z4; }
    {
        const int s0 = (lg & 1)*32 + lr;
        const int s1_ = s0 + 16;
        const bool hi = (lg >> 1) != 0;
#pragma unroll
        for (int hd = 0; hd < 4; hd++) {
            unsigned a00 = __shfl(pa[hd].x, s0), a01 = __shfl(pa[hd].y, s0);
            unsigned a10 = __shfl(pa[hd].x, s1_), a11 = __shfl(pa[hd].y, s1_);
            union { unsigned u[4]; bf16x8 v; } af;
            af.u[0] = hi ? 0u : a00; af.u[1] = hi ? 0u : a01;
            af.u[2] = hi ? 0u : a10; af.u[3] = hi ? 0u : a11;
#pragma unroll
            for (int dt = 0; dt < 2; dt++) {
                bf16x8 bv = *(const bf16x8*)&vbT[(hd*32+dt*16+lr)*24 + (lg&1)*8];
                aacc[hd][dt] = __builtin_amdgcn_mfma_f32_16x16x32_bf16(af.v, bv, aacc[hd][dt], 0, 0, 0);
            }
        }
    }
    FENCE();
#pragma unroll
    for (int hd = 0; hd < 4; hd++)
#pragma unroll
        for (int dt = 0; dt < 2; dt++)
#pragma unroll
            for (int rr = 0; rr < 4; rr++)
                aT[(wtb + lg*4 + rr)*136 + hd*32 + dt*16 + lr]
                    = f2bf(aacc[hd][dt][rr]);
    FENCE();

    f32x4 acc[8];
#pragma unroll
    for (int nf = 0; nf < 8; nf++) acc[nf] = z4;
#pragma unroll
    for (int kst = 0; kst < 4; kst++) {
        bf16x8 a = *(const bf16x8*)&aT[(wtb+lr)*136 + kst*32 + lg*8];
#pragma unroll
        for (int nf = 0; nf < 8; nf++) {
            bf16x8 b = *(const bf16x8*)&wpp[(nf*16+lr)*128 + kst*32 + lg*8];
            acc[nf] = __builtin_amdgcn_mfma_f32_16x16x32_bf16(a, b, acc[nf], 0, 0, 0);
        }
    }
#pragma unroll
    for (int nf = 0; nf < 8; nf++) {
        float bpv = bp[nf*16 + lr];
#pragma unroll
        for (int rr = 0; rr < 4; rr++) {
            int tt = wtb + lg*4 + rr;
            int hh = wx*16 + rg*4 + (tt >> 4), ww = wy*16 + (tt & 15);
            int gi = (hh*256+ww)*128 + nf*16 + lr;
            z2[gi] = acc[nf][rr] + bpv + z1[gi];   // exact f32 residual
        }
    }
}

// ---------------- kernel 5/7: residual MLP, split-hidden (bit-exact) --------
__global__ __launch_bounds__(256) void k_mlp(
    float* __restrict__ z,
    const float* __restrict__ g, const float* __restrict__ bta,
    const unsigned short* __restrict__ w1p, const float* __restrict__ b1,
    const unsigned short* __restrict__ w2p, const float* __restrict__ b2)
{
    __shared__ __align__(16) unsigned short aT[64*136];
    __shared__ __align__(16) unsigned short hT[64*136];   // half-hidden tile
    const int base = blockIdx.x * 64;
    const int tid = threadIdx.x;
    const int t = tid >> 2, part = tid & 3;

    const float* zr = z + (base + t)*128 + part*32;
    float r[32]; float s1 = 0.f, s2 = 0.f;
#pragma unroll
    for (int k4 = 0; k4 < 8; k4++) {
        float4 v = *(const float4*)&zr[k4*4];
        r[k4*4+0]=v.x; r[k4*4+1]=v.y; r[k4*4+2]=v.z; r[k4*4+3]=v.w;
        s1 += v.x+v.y+v.z+v.w;
        s2 += v.x*v.x+v.y*v.y+v.z*v.z+v.w*v.w;
    }
    s1 += __shfl_xor(s1, 1); s1 += __shfl_xor(s1, 2);
    s2 += __shfl_xor(s2, 1); s2 += __shfl_xor(s2, 2);
    const float mean = s1*(1.f/128.f);
    const float var  = s2*(1.f/128.f) - mean*mean;
    const float rstd = rsqrtf(var + LN_EPS);
#pragma unroll
    for (int k4 = 0; k4 < 8; k4++) {
        int c = part*32 + k4*4;
        ushort4 u;
        u.x = f2bf((r[k4*4+0]-mean)*rstd*g[c+0] + bta[c+0]);
        u.y = f2bf((r[k4*4+1]-mean)*rstd*g[c+1] + bta[c+1]);
        u.z = f2bf((r[k4*4+2]-mean)*rstd*g[c+2] + bta[c+2]);
        u.w = f2bf((r[k4*4+3]-mean)*rstd*g[c+3] + bta[c+3]);
        *(ushort4*)&aT[t*136 + c] = u;
    }
    __syncthreads();

    const int lane = tid & 63, wid = tid >> 6;
    const int lr = lane & 15, lg = lane >> 4;
    const int wtb = wid * 16;
    const f32x4 z4 = {0.f, 0.f, 0.f, 0.f};

    f32x4 oacc[8];
#pragma unroll
    for (int nf = 0; nf < 8; nf++) oacc[nf] = z4;

#pragma unroll
    for (int half = 0; half < 2; half++) {
        // stage 1: hidden half (128 wide) = A @ W1[half]^T, gelu -> hT
        f32x4 acc[8];
#pragma unroll
        for (int nf = 0; nf < 8; nf++) acc[nf] = z4;
#pragma unroll
        for (int kst = 0; kst < 4; kst++) {
            bf16x8 a = *(const bf16x8*)&aT[(wtb+lr)*136 + kst*32 + lg*8];
#pragma unroll
            for (int nf = 0; nf < 8; nf++) {
                bf16x8 b = *(const bf16x8*)&w1p[((half*8+nf)*16+lr)*128 + kst*32 + lg*8];
                acc[nf] = __builtin_amdgcn_mfma_f32_16x16x32_bf16(a, b, acc[nf], 0, 0, 0);
            }
        }
#pragma unroll
        for (int nf = 0; nf < 8; nf++) {
            float bb = b1[(half*8+nf)*16 + lr];
#pragma unroll
            for (int rr = 0; rr < 4; rr++) {
                float hv = acc[nf][rr] + bb;
                float gl = 0.5f*hv*(1.f + erff(hv*0.70710678118f));
                hT[(wtb + lg*4 + rr)*136 + nf*16 + lr] = f2bf(gl);
            }
        }
        FENCE();   // wave-private rows

        // stage 2: accumulate out += H_half @ W2[:, half]^T
#pragma unroll
        for (int kst = 0; kst < 4; kst++) {
            bf16x8 a = *(const bf16x8*)&hT[(wtb+lr)*136 + kst*32 + lg*8];
#pragma unroll
            for (int nf = 0; nf < 8; nf++) {
                bf16x8 b = *(const bf16x8*)&w2p[(nf*16+lr)*256 + half*128 + kst*32 + lg*8];
                oacc[nf] = __builtin_amdgcn_mfma_f32_16x16x32_bf16(a, b, oacc[nf], 0, 0, 0);
            }
        }
        FENCE();   // hT reads complete before next half overwrites
    }

#pragma unroll
    for (int nf = 0; nf < 8; nf++) {
        float bb = b2[nf*16 + lr];
#pragma unroll
        for (int rr = 0; rr < 4; rr++) {
            int idx = (base + wtb + lg*4 + rr)*128 + nf*16 + lr;
            z[idx] = z[idx] + oacc[nf][rr] + bb;
        }
    }
}

// ---------------- kernel 8: final LN + transpose to (128,256,256) -----------
__global__ __launch_bounds__(256) void k_post(
    const float* __restrict__ z2,
    const float* __restrict__ g, const float* __restrict__ b,
    float* __restrict__ out)
{
    __shared__ float buf[64][129];
    const int blk = blockIdx.x;           // h*4 + quarter
    const int h = blk >> 2, w0 = (blk & 3)*64;
    const int tid = threadIdx.x;
    const int t = tid >> 2, part = tid & 3;

    const float* zr = z2 + (h*256 + w0 + t)*128 + part*32;
    float r[32]; float s1 = 0.f, s2 = 0.f;
#pragma unroll
    for (int k4 = 0; k4 < 8; k4++) {
        float4 v = *(const float4*)&zr[k4*4];
        r[k4*4+0]=v.x; r[k4*4+1]=v.y; r[k4*4+2]=v.z; r[k4*4+3]=v.w;
        s1 += v.x+v.y+v.z+v.w;
        s2 += v.x*v.x+v.y*v.y+v.z*v.z+v.w*v.w;
    }
    s1 += __shfl_xor(s1, 1); s1 += __shfl_xor(s1, 2);
    s2 += __shfl_xor(s2, 1); s2 += __shfl_xor(s2, 2);
    const float mean = s1*(1.f/128.f);
    const float var  = s2*(1.f/128.f) - mean*mean;
    const float rstd = rsqrtf(var + LN_EPS);
#pragma unroll
    for (int k = 0; k < 32; k++) {
        int c = part*32 + k;
        buf[t][c] = (r[k]-mean)*rstd*g[c] + b[c];
    }
    __syncthreads();
    for (int idx = tid; idx < 64*128; idx += 256) {
        int c = idx >> 6, wl = idx & 63;
        out[(c*256 + h)*256 + w0 + wl] = buf[wl][c];
    }
}

// ============================================================================
extern "C" void kernel_launch(void* const* d_in, const int* in_sizes, int n_in,
                              void* d_out, int out_size, void* d_ws, size_t ws_size,
                              hipStream_t stream)
{
    (void)in_sizes; (void)n_in; (void)out_size; (void)ws_size;
    const float* x       = (const float*)d_in[1];
    const float* feature = (const float*)d_in[2];
    const float* I_inv   = (const float*)d_in[3];
    const float* E_inv   = (const float*)d_in[4];
    const float* fl_g = (const float*)d_in[5],  *fl_b = (const float*)d_in[6];
    const float* fl_m = (const float*)d_in[7],  *fl_v = (const float*)d_in[8];
    const float* fl_w = (const float*)d_in[9];
    const float* fp_g = (const float*)d_in[10], *fp_b = (const float*)d_in[11];
    const float* fp_m = (const float*)d_in[12], *fp_v = (const float*)d_in[13];
    const float* fp_w = (const float*)d_in[14];
    const float* bev_w = (const float*)d_in[15], *bev_b = (const float*)d_in[16];
    const float* img_w = (const float*)d_in[17], *cam_w = (const float*)d_in[18];
    const float* a1_nq_g = (const float*)d_in[19], *a1_nq_b = (const float*)d_in[20];
    const float* a1_wq = (const float*)d_in[21], *a1_bq = (const float*)d_in[22];
    const float* a1_nk_g = (const float*)d_in[23], *a1_nk_b = (const float*)d_in[24];
    const float* a1_wk = (const float*)d_in[25], *a1_bk = (const float*)d_in[26];
    const float* a1_nv_g = (const float*)d_in[27], *a1_nv_b = (const float*)d_in[28];
    const float* a1_wv = (const float*)d_in[29], *a1_bv = (const float*)d_in[30];
    const float* a1_wp = (const float*)d_in[31], *a1_bp = (const float*)d_in[32];
    const float* pn1_g = (const float*)d_in[33], *pn1_b = (const float*)d_in[34];
    const float* m1_w1 = (const float*)d_in[35], *m1_b1 = (const float*)d_in[36];
    const float* m1_w2 = (const float*)d_in[37], *m1_b2 = (const float*)d_in[38];
    const float* a2_nq_g = (const float*)d_in[39], *a2_nq_b = (const float*)d_in[40];
    const float* a2_wq = (const float*)d_in[41], *a2_bq = (const float*)d_in[42];
    const float* a2_nk_g = (const float*)d_in[43], *a2_nk_b = (const float*)d_in[44];
    const float* a2_wk = (const float*)d_in[45], *a2_bk = (const float*)d_in[46];
    const float* a2_nv_g = (const float*)d_in[47], *a2_nv_b = (const float*)d_in[48];
    const float* a2_wv = (const float*)d_in[49], *a2_bv = (const float*)d_in[50];
    const float* a2_wp = (const float*)d_in[51], *a2_bp = (const float*)d_in[52];
    const float* pn2_g = (const float*)d_in[53], *pn2_b = (const float*)d_in[54];
    const float* m2_w1 = (const float*)d_in[55], *m2_b1 = (const float*)d_in[56];
    const float* m2_w2 = (const float*)d_in[57], *m2_b2 = (const float*)d_in[58];
    const float* post_g = (const float*)d_in[59], *post_b = (const float*)d_in[60];

    float* ws  = (float*)d_ws;
    unsigned short* pk = (unsigned short*)ws;
    const unsigned short* wp1p  = pk + 16384;
    const unsigned short* wp2p  = pk + 49152;
    const unsigned short* m1w1p = pk + 65536;
    const unsigned short* m1w2p = pk + 98304;
    const unsigned short* m2w1p = pk + 131072;
    const unsigned short* m2w2p = pk + 163840;
    const unsigned short* fpwp  = pk + 196608;
    const unsigned short* flwp  = pk + 212992;
    const unsigned short* wk1p  = pk + 229376;
    const unsigned short* wv1p  = pk + 245760;
    const unsigned short* wk2p  = pk + 262144;
    const unsigned short* wv2p  = pk + 278528;
    const unsigned short* wq1Tp = pk + 294912;
    const unsigned short* wq2Tp = pk + 311296;

    float* cb  = ws + 163840;                       // [4][128]
    float* Mb1 = ws + 164352;                       // [256][64]
    float* Mb2 = ws + 180736;
    float* kp2 = ws + 197120;                       // live through mwin
    float* vp2 = ws + 721408;                       // live through attn2
    unsigned short* Mw2 = (unsigned short*)(ws + 1245696);  // ends 2294272
    float* kp1 = ws + 2294272;                      // dead after mwin
    float* vp1 = ws + 2818560;                      // dead after attn1
    unsigned short* Mw1 = (unsigned short*)(ws + 3342848);  // ends 4391424
    float* key = ws + 3342848;                      // aliases Mw1 (dead first)
    float* val = ws + 3867136;
    float* img = ws + 4391424;
    float* z2  = ws + 2294272;                      // overlaps dead kp1..img
    float* z1  = (float*)d_out;

    k_pack<<<1283, 256, 0, stream>>>(pk, cb,
        a1_wq, a1_wp, a2_wq, a2_wp, m1_w1, m1_w2, m2_w1, m2_w2,
        fp_w, fl_w, a1_wk, a1_wv, a2_wk, a2_wv, bev_b, cam_w, E_inv);
    k_img_embed<<<4096, 128, 0, stream>>>(I_inv, E_inv, img_w, cam_w, img);
    k_keyval<<<64, 256, 0, stream>>>(feature, img,
                                     fp_g, fp_b, fp_m, fp_v, fpwp,
                                     fl_g, fl_b, fl_m, fl_v, flwp,
                                     key, val);
    k_kvproj<<<256, 256, 0, stream>>>(key, val,
                                      a1_nk_g, a1_nk_b, wk1p, a1_bk,
                                      a1_nv_g, a1_nv_b, wv1p, a1_bv,
                                      a2_nk_g, a2_nk_b, wk2p, a2_bk,
                                      a2_nv_g, a2_nv_b, wv2p, a2_bv,
                                      kp1, vp1, kp2, vp2);
    k_mwin<<<512, 256, 0, stream>>>(kp1, kp2, wq1Tp, wq2Tp, a1_bq, a2_bq,
                                    Mw1, Mw2, Mb1, Mb2);
    k_attn1<<<1024, 256, 0, stream>>>(x, vp1, Mw1, Mb1, bev_w, cb,
                                      a1_nq_g, a1_nq_b, wp1p, a1_bp, z1);
    k_mlp<<<1024, 256, 0, stream>>>(z1, pn1_g, pn1_b, m1w1p, m1_b1, m1w2p, m1_b2);
    k_attn2<<<1024, 256, 0, stream>>>(z1, vp2, Mw2, Mb2,
                                      a2_nq_g, a2_nq_b, wp2p, a2_bp, z2);
    k_mlp<<<1024, 256, 0, stream>>>(z2, pn2_g, pn2_b, m2w1p, m2_b1, m2w2p, m2_b2);
    k_post<<<1024, 256, 0, stream>>>(z2, post_g, post_b, (float*)d_out);
}